// Round 12
// baseline (114.926 us; speedup 1.0000x reference)
//
#include <hip/hip_runtime.h>

// Problem constants
#define B_SZ  4
#define C_IN  256
#define N_POS 4096     // H*W = 64*64
#define NH    2
#define HC    64       // hidden per head

typedef __attribute__((ext_vector_type(8))) __bf16 bf16x8;
typedef __attribute__((ext_vector_type(4))) float  f32x4;
typedef unsigned short u16;

__device__ __forceinline__ u16 f2bf(float f) {
  unsigned u = __float_as_uint(f);
  u = u + 0x7FFF + ((u >> 16) & 1);   // round-nearest-even
  return (u16)(u >> 16);
}

#if __has_builtin(__builtin_amdgcn_exp2f)
  #define EXP2(x) __builtin_amdgcn_exp2f(x)
#else
  #define EXP2(x) exp2f(x)
#endif

// packed f32x2 -> bf16x2 (RNE), low half = src0
__device__ __forceinline__ unsigned cvtpk_bf16(float lo, float hi) {
  unsigned r;
  asm("v_cvt_pk_bf16_f32 %0, %1, %2" : "=v"(r) : "v"(lo), "v"(hi));
  return r;
}

// async global->LDS 16B per lane (dest = wave-uniform base + lane*16)
__device__ __forceinline__ void gload_lds16(const void* g, void* l) {
  __builtin_amdgcn_global_load_lds(
      (const __attribute__((address_space(1))) unsigned*)g,
      (__attribute__((address_space(3))) unsigned*)l, 16, 0, 0);
}

// ---------------------------------------------------------------------------
// Kernel 0b: cast embed_w -> wbf [384][256] bf16 ; transpose out_w -> w2t [256][128] bf16
// ---------------------------------------------------------------------------
__global__ __launch_bounds__(256) void k_prep_w(const float* __restrict__ ew,
                                                const float* __restrict__ ow,
                                                u16* __restrict__ wbf,
                                                u16* __restrict__ w2t) {
  int i = blockIdx.x * 256 + threadIdx.x;
  if (i < 384 * 256) wbf[i] = f2bf(ew[i]);
  if (i < 128 * 256) {
    int d = i >> 8, c = i & 255;              // out_w[d][c]
    w2t[c * 128 + d] = f2bf(ow[i]);
  }
}

// ---------------------------------------------------------------------------
// Kernel 1: fused transpose + QKV projection (round-10 proven).
//   q -> Qt [bh][N][64] (n-major, pre-scaled by C^-0.5 * log2(e))
//   k -> Kt [bh][N][64] (n-major)
//   v -> Vs [bh][nt(64)][kk(2)][lg(4)][c(64)][8]  (PV-fragment order)
// ---------------------------------------------------------------------------
__global__ __launch_bounds__(256) void k_qkv(const float* __restrict__ x,
                                             const u16* __restrict__ wbf,
                                             const float* __restrict__ eb,
                                             u16* __restrict__ Qt,
                                             u16* __restrict__ Kt,
                                             u16* __restrict__ Vs) {
  int id = blockIdx.x;          // 512
  int xcd = id & 7;
  int b = xcd >> 1, h = xcd & 1;
  int nt = id >> 3;             // 0..63
  int tid = threadIdx.x;        // 0..255
  int w = tid >> 6, l = tid & 63, lr = l & 15, lg = l >> 4;

  __shared__ __align__(16) u16 Xl[64 * 256];   // 32 KB: Xl[n][c], slot-swizzled

  const float* xb = x + (size_t)b * C_IN * N_POS + nt*64;
  {
    int n = l;                   // lane = n
#pragma unroll
    for (int pass = 0; pass < 8; pass++) {
      int oct = w + pass*4;      // c-oct 0..31 (8 channels each)
      int cb8 = oct * 8;
      float v[8];
#pragma unroll
      for (int j = 0; j < 8; j++) v[j] = xb[(size_t)(cb8 + j) * N_POS + n];
      union { bf16x8 vv; unsigned u[4]; } pk;
#pragma unroll
      for (int jj = 0; jj < 4; jj++) pk.u[jj] = cvtpk_bf16(v[2*jj], v[2*jj+1]);
      int slot = oct ^ ((n & 7) << 2);
      *(bf16x8*)&Xl[n * 256 + slot * 8] = pk.vv;
    }
  }
  __syncthreads();

  f32x4 acc[4][3] = {};
  const u16* brow[3];
#pragma unroll
  for (int i = 0; i < 3; i++)
    brow[i] = wbf + (size_t)(h*192 + (3*w + i)*16 + lr) * C_IN + lg*8;

#pragma unroll
  for (int kk = 0; kk < 8; kk++) {
    bf16x8 bfr[3];
#pragma unroll
    for (int i = 0; i < 3; i++) bfr[i] = *(const bf16x8*)(brow[i] + kk*32);
#pragma unroll
    for (int nsub = 0; nsub < 4; nsub++) {
      int n2 = nsub*16 + lr;
      int sp = (kk*4 + lg) ^ ((lr & 7) << 2);
      bf16x8 a = *(const bf16x8*)&Xl[n2*256 + sp*8];
#pragma unroll
      for (int i = 0; i < 3; i++)
        acc[nsub][i] = __builtin_amdgcn_mfma_f32_16x16x32_bf16(a, bfr[i], acc[nsub][i], 0, 0, 0);
    }
  }

  const float QSCALE = 0.0625f * 1.44269504088896f;  // C^-0.5 * log2(e)
  int bh = b * NH + h;
#pragma unroll
  for (int i = 0; i < 3; i++) {
    int s3 = 3*w + i;
    int type = s3 >> 2, mf = s3 & 3;
    int cl = mf*16 + lr;                       // channel within head [0,64)
    float bias = eb[h*192 + type*64 + cl];
#pragma unroll
    for (int nsub = 0; nsub < 4; nsub++) {
      int n0 = nt*64 + nsub*16 + lg*4;         // 4 consecutive n (regs)
      if (type == 0) {
        u16* q = Qt + (size_t)bh * N_POS * HC;
#pragma unroll
        for (int r = 0; r < 4; r++) q[(size_t)(n0+r)*HC + cl] = f2bf((acc[nsub][i][r] + bias) * QSCALE);
      } else if (type == 1) {
        u16* kd = Kt + (size_t)bh * N_POS * HC;
#pragma unroll
        for (int r = 0; r < 4; r++) kd[(size_t)(n0+r)*HC + cl] = f2bf(acc[nsub][i][r] + bias);
      } else {
        u16* vd = Vs + (size_t)bh * (N_POS * HC);
        size_t idx = ((((size_t)nt*2 + (nsub>>1))*4 + lg)*64 + cl)*8 + 4*(nsub&1);
        ushort4 pk;
        pk.x = f2bf(acc[nsub][i][0] + bias);
        pk.y = f2bf(acc[nsub][i][1] + bias);
        pk.z = f2bf(acc[nsub][i][2] + bias);
        pk.w = f2bf(acc[nsub][i][3] + bias);
        *(ushort4*)(vd + idx) = pk;
      }
    }
  }
}

// ---------------------------------------------------------------------------
// Kernel 2: flash attention (round-10 proven structure + defer-max T13).
// 16 waves = 4 qi x 4 ci, QBLK=32 rows/wave, double-buffered global_load_lds
// staging, grid 256, setprio on MFMA clusters, rotated conflict-free merge.
// Defer-max: skip rescale while __all(mx <= rm + 8); P <= 2^8, bf16-safe;
// merge stays exact (rm still tracked).
// ---------------------------------------------------------------------------
__device__ __forceinline__ void softmax_defer(f32x4 (&s)[4], f32x4& psv, float& rm,
                                              f32x4 (&o)[4]) {
  float mx = s[0][0];
#pragma unroll
  for (int nf = 0; nf < 4; nf++)
#pragma unroll
    for (int r = 0; r < 4; r++) mx = fmaxf(mx, s[nf][r]);
  mx = fmaxf(mx, __shfl_xor(mx, 16));
  mx = fmaxf(mx, __shfl_xor(mx, 32));
  if (__all(mx <= rm + 8.0f)) {
    // fast path: no rescale; P = exp2(s - rm) bounded by 2^8
#pragma unroll
    for (int nf = 0; nf < 4; nf++)
#pragma unroll
      for (int r = 0; r < 4; r++) {
        float p = EXP2(s[nf][r] - rm);
        s[nf][r] = p;
        psv[r] += p;
      }
  } else {
    float nm = fmaxf(rm, mx);
    float corr = EXP2(rm - nm);
    rm = nm;
#pragma unroll
    for (int r = 0; r < 4; r++) psv[r] *= corr;
#pragma unroll
    for (int nf = 0; nf < 4; nf++)
#pragma unroll
      for (int r = 0; r < 4; r++) {
        float p = EXP2(s[nf][r] - nm);
        s[nf][r] = p;
        psv[r] += p;
      }
#pragma unroll
    for (int cf = 0; cf < 4; cf++)
#pragma unroll
      for (int r = 0; r < 4; r++) o[cf][r] *= corr;
  }
}

__global__ __launch_bounds__(1024, 4) void k_attn(const u16* __restrict__ Qt,
                                                  const u16* __restrict__ Kt,
                                                  const u16* __restrict__ Vs,
                                                  u16* __restrict__ Ot) {
  int id = blockIdx.x;            // 256
  int bh = id & 7;                // XCD-swizzle: one (b,h) per XCD
  int mt = id >> 3;               // 32 q-tiles of 128 rows
  int b = bh >> 1, h = bh & 1;
  int tid = threadIdx.x;
  int wid = tid >> 6;             // 0..15
  int l = tid & 63, lr = l & 15, lg = l >> 4;
  int qi = wid & 3;               // 32-row q-subtile
  int ci = wid >> 2;              // KV chunk (16 tiles of 64 = 1024 positions)
  int m0 = mt*128 + qi*32;

  // 128KB staging: [buf2][ci4][ K 8KB | V 8KB ]; merge overlays after loop
  __shared__ __align__(16) char smem[131072];
  __shared__ float Lps[4][8][16];
  __shared__ float Lm[4][8][16];

  bf16x8 qf[2][2];
#pragma unroll
  for (int sub = 0; sub < 2; sub++) {
    const u16* qb = Qt + ((size_t)bh * N_POS + m0 + sub*16 + lr) * HC + lg*8;
    qf[sub][0] = *(const bf16x8*)qb;
    qf[sub][1] = *(const bf16x8*)(qb + 32);
  }

  const char* Kt_bh = (const char*)(Kt + (size_t)bh * N_POS * HC);
  const char* Vs_bh = (const char*)(Vs + (size_t)bh * N_POS * HC);
  int gtid = tid & 255;           // index within ci staging group (256 threads)

  f32x4 o0[4] = {}, o1[4] = {};
  f32x4 ps0 = {}, ps1 = {};
  float rm0 = -1e30f, rm1 = -1e30f;
  int xr = (lr & 7) << 4;         // K read swizzle

  union PF { bf16x8 v; unsigned u[4]; };

  // stage tile -> LDS: K with inverse-swizzled SOURCE (linear dest), V linear
  auto stage = [&](int tile, char* sb) {
    const char* ksrc = Kt_bh + (size_t)tile * 8192;
    const char* vsrc = Vs_bh + (size_t)tile * 8192;
#pragma unroll
    for (int j = 0; j < 2; j++) {
      int off = (j*256 + gtid) * 16;
      int koff = off ^ (((off >> 7) & 7) << 4);
      gload_lds16(ksrc + koff, sb + off);
      gload_lds16(vsrc + off, sb + 8192 + off);
    }
  };

  stage(ci*16, smem + ci*16384);
  __syncthreads();

  int buf = 0;
  for (int t = 0; t < 16; t++) {
    if (t < 15) stage(ci*16 + t + 1, smem + (buf^1)*65536 + ci*16384);

    const char* Kb = smem + buf*65536 + ci*16384;
    const char* Vb = Kb + 8192;

    // ---- S^T = K . Q^T for both q-subtiles (K read once) ----
    f32x4 s0[4], s1[4];
    __builtin_amdgcn_s_setprio(1);
#pragma unroll
    for (int nf = 0; nf < 4; nf++) {
      const char* kr = Kb + (nf*16 + lr) * 128;
      bf16x8 k0 = *(const bf16x8*)(kr + ((lg*16)      ^ xr));
      bf16x8 k1 = *(const bf16x8*)(kr + ((lg*16 + 64) ^ xr));
      f32x4 z0 = {}, z1 = {};
      z0 = __builtin_amdgcn_mfma_f32_16x16x32_bf16(k0, qf[0][0], z0, 0, 0, 0);
      s0[nf] = __builtin_amdgcn_mfma_f32_16x16x32_bf16(k1, qf[0][1], z0, 0, 0, 0);
      z1 = __builtin_amdgcn_mfma_f32_16x16x32_bf16(k0, qf[1][0], z1, 0, 0, 0);
      s1[nf] = __builtin_amdgcn_mfma_f32_16x16x32_bf16(k1, qf[1][1], z1, 0, 0, 0);
    }
    __builtin_amdgcn_s_setprio(0);

    softmax_defer(s0, ps0, rm0, o0);
    softmax_defer(s1, ps1, rm1, o1);

    // ---- O^T += V^T . P (V read once, feeds both subtiles) ----
    __builtin_amdgcn_s_setprio(1);
#pragma unroll
    for (int kk = 0; kk < 2; kk++) {
      PF pa, pb;
      pa.u[0] = cvtpk_bf16(s0[2*kk+0][0], s0[2*kk+0][1]);
      pa.u[1] = cvtpk_bf16(s0[2*kk+0][2], s0[2*kk+0][3]);
      pa.u[2] = cvtpk_bf16(s0[2*kk+1][0], s0[2*kk+1][1]);
      pa.u[3] = cvtpk_bf16(s0[2*kk+1][2], s0[2*kk+1][3]);
      pb.u[0] = cvtpk_bf16(s1[2*kk+0][0], s1[2*kk+0][1]);
      pb.u[1] = cvtpk_bf16(s1[2*kk+0][2], s1[2*kk+0][3]);
      pb.u[2] = cvtpk_bf16(s1[2*kk+1][0], s1[2*kk+1][1]);
      pb.u[3] = cvtpk_bf16(s1[2*kk+1][2], s1[2*kk+1][3]);
#pragma unroll
      for (int cf = 0; cf < 4; cf++) {
        bf16x8 vf = *(const bf16x8*)(Vb + (kk*4 + lg)*1024 + (cf*16 + lr)*16);
        o0[cf] = __builtin_amdgcn_mfma_f32_16x16x32_bf16(vf, pa.v, o0[cf], 0, 0, 0);
        o1[cf] = __builtin_amdgcn_mfma_f32_16x16x32_bf16(vf, pb.v, o1[cf], 0, 0, 0);
      }
    }
    __builtin_amdgcn_s_setprio(0);

    __syncthreads();   // drains vmcnt -> next buffer ready
    buf ^= 1;
  }

  // ---- chunk-partial row sums ----
  float psa = ps0[0] + ps0[1] + ps0[2] + ps0[3];
  psa += __shfl_xor(psa, 16);
  psa += __shfl_xor(psa, 32);
  float psb = ps1[0] + ps1[1] + ps1[2] + ps1[3];
  psb += __shfl_xor(psb, 16);
  psb += __shfl_xor(psb, 32);

  // ---- write partials (Lo overlays staging LDS; row-rotated cols) ----
  float (*Lo)[8][16][64] = (float (*)[8][16][64])smem;
#pragma unroll
  for (int cf = 0; cf < 4; cf++) {
    int colw = ((cf*16 + 4*lg) + 4*lr) & 63;
    *(f32x4*)&Lo[ci][qi*2+0][lr][colw] = o0[cf];
    *(f32x4*)&Lo[ci][qi*2+1][lr][colw] = o1[cf];
  }
  if (lg == 0) {
    Lps[ci][qi*2+0][lr] = psa; Lm[ci][qi*2+0][lr] = rm0;
    Lps[ci][qi*2+1][lr] = psb; Lm[ci][qi*2+1][lr] = rm1;
  }
  __syncthreads();

  // ---- exact flash merge of 4 chunks + normalize + write Ot [B][N][128] ----
  int row = tid >> 3;             // 0..127 within this q-tile
  int c0 = (tid & 7) * 8;         // 0..56
  int g = row >> 4, r2 = row & 15;
  float m0_ = Lm[0][g][r2], m1_ = Lm[1][g][r2];
  float m2_ = Lm[2][g][r2], m3_ = Lm[3][g][r2];
  float M = fmaxf(fmaxf(m0_, m1_), fmaxf(m2_, m3_));
  float w0 = EXP2(m0_ - M), w1 = EXP2(m1_ - M);
  float w2 = EXP2(m2_ - M), w3 = EXP2(m3_ - M);
  int ca = (c0 + 4*r2) & 63;      // rotated col of channels c0..c0+3
  int cb = (c0 + 4 + 4*r2) & 63;  // rotated col of channels c0+4..c0+7
  f32x4 accA, accB;
  {
    f32x4 a0 = *(const f32x4*)&Lo[0][g][r2][ca];
    f32x4 a1 = *(const f32x4*)&Lo[1][g][r2][ca];
    f32x4 a2 = *(const f32x4*)&Lo[2][g][r2][ca];
    f32x4 a3 = *(const f32x4*)&Lo[3][g][r2][ca];
#pragma unroll
    for (int i = 0; i < 4; i++) accA[i] = a0[i]*w0 + a1[i]*w1 + a2[i]*w2 + a3[i]*w3;
    f32x4 b0 = *(const f32x4*)&Lo[0][g][r2][cb];
    f32x4 b1 = *(const f32x4*)&Lo[1][g][r2][cb];
    f32x4 b2 = *(const f32x4*)&Lo[2][g][r2][cb];
    f32x4 b3 = *(const f32x4*)&Lo[3][g][r2][cb];
#pragma unroll
    for (int i = 0; i < 4; i++) accB[i] = b0[i]*w0 + b1[i]*w1 + b2[i]*w2 + b3[i]*w3;
  }
  float pst = Lps[0][g][r2]*w0 + Lps[1][g][r2]*w1
            + Lps[2][g][r2]*w2 + Lps[3][g][r2]*w3;
  float rinv = 1.0f / pst;
  u16* ob = Ot + ((size_t)b * N_POS + mt*128 + row) * (NH*HC) + h*HC + c0;
  uint4 st;
  st.x = cvtpk_bf16(accA[0]*rinv, accA[1]*rinv);
  st.y = cvtpk_bf16(accA[2]*rinv, accA[3]*rinv);
  st.z = cvtpk_bf16(accB[0]*rinv, accB[1]*rinv);
  st.w = cvtpk_bf16(accB[2]*rinv, accB[3]*rinv);
  *(uint4*)ob = st;
}

// ---------------------------------------------------------------------------
// Kernel 3: out[b][c][n] = sum_d Ot[n][d] * w2t[c][d] + out_b[c] + x[b][c][n]
// ---------------------------------------------------------------------------
__global__ __launch_bounds__(256) void k_out(const u16* __restrict__ Ot,
                                             const u16* __restrict__ w2t,
                                             const float* __restrict__ obias,
                                             const float* __restrict__ x,
                                             float* __restrict__ out) {
  int b = blockIdx.z;   // 4
  int ct = blockIdx.y;  // 4
  int nt = blockIdx.x;  // 64
  int w = threadIdx.x >> 6, l = threadIdx.x & 63;
  int lr = l & 15, lg = l >> 4;

  const u16* arow = Ot + ((size_t)b * N_POS + nt*64 + w*16 + lr) * 128 + lg*8;
  const u16* brow = w2t + ((size_t)(ct*64) + lr) * 128 + lg*8;

  f32x4 acc[4] = {};
#pragma unroll
  for (int kk = 0; kk < 4; kk++) {
    bf16x8 a = *(const bf16x8*)(arow + kk*32);
#pragma unroll
    for (int cf = 0; cf < 4; cf++) {
      bf16x8 bf = *(const bf16x8*)(brow + (size_t)cf*16*128 + kk*32);
      acc[cf] = __builtin_amdgcn_mfma_f32_16x16x32_bf16(a, bf, acc[cf], 0, 0, 0);
    }
  }

  int n0 = nt*64 + w*16 + lg*4;
#pragma unroll
  for (int cf = 0; cf < 4; cf++) {
    int c = ct*64 + cf*16 + lr;
    float bias = obias[c];
    const float* xp = x + ((size_t)b * C_IN + c) * N_POS + n0;
    float* op = out + ((size_t)b * C_IN + c) * N_POS + n0;
    f32x4 xv = *(const f32x4*)xp;
    f32x4 rv;
#pragma unroll
    for (int i = 0; i < 4; i++) rv[i] = acc[cf][i] + bias + xv[i];
    *(f32x4*)op = rv;
  }
}

// ---------------------------------------------------------------------------
extern "C" void kernel_launch(void* const* d_in, const int* in_sizes, int n_in,
                              void* d_out, int out_size, void* d_ws, size_t ws_size,
                              hipStream_t stream) {
  const float* x  = (const float*)d_in[0];   // [4,256,64,64]
  const float* ew = (const float*)d_in[1];   // [2,192,256]
  const float* eb = (const float*)d_in[2];   // [2,192]
  const float* ow = (const float*)d_in[3];   // [128,256]
  const float* ob = (const float*)d_in[4];   // [256]
  float* out = (float*)d_out;

  char* ws = (char*)d_ws;
  u16* wbf = (u16*)(ws + 0);          //    196,608 B  embed_w bf16 [384][256]
  u16* w2t = (u16*)(ws + 196608);     //     65,536 B  out_w^T bf16 [256][128]
  u16* Qt  = (u16*)(ws + 262144);     //  4,194,304 B  [8][4096][64]
  u16* Kt  = (u16*)(ws + 4456448);    //  4,194,304 B  [8][4096][64]
  u16* Vs  = (u16*)(ws + 8650752);    //  4,194,304 B  permuted V
  u16* Ot  = (u16*)(ws + 12845056);   //  4,194,304 B  [B][N][128]

  hipLaunchKernelGGL(k_prep_w, dim3(384), dim3(256), 0, stream, ew, ow, wbf, w2t);
  hipLaunchKernelGGL(k_qkv,  dim3(512),      dim3(256), 0, stream, x, wbf, eb, Qt, Kt, Vs);
  hipLaunchKernelGGL(k_attn, dim3(256),      dim3(1024), 0, stream, Qt, Kt, Vs, Ot);
  hipLaunchKernelGGL(k_out,  dim3(64, 4, 4), dim3(256), 0, stream, Ot, w2t, ob, x, out);
}

// Round 13
// 88.139 us; speedup vs baseline: 1.3039x; 1.3039x over previous
//
#include <hip/hip_runtime.h>

// Problem constants
#define B_SZ  4
#define C_IN  256
#define N_POS 4096     // H*W = 64*64
#define NH    2
#define HC    64       // hidden per head

typedef __attribute__((ext_vector_type(8))) __bf16 bf16x8;
typedef __attribute__((ext_vector_type(4))) float  f32x4;
typedef unsigned short u16;

__device__ __forceinline__ u16 f2bf(float f) {
  unsigned u = __float_as_uint(f);
  u = u + 0x7FFF + ((u >> 16) & 1);   // round-nearest-even
  return (u16)(u >> 16);
}

#if __has_builtin(__builtin_amdgcn_exp2f)
  #define EXP2(x) __builtin_amdgcn_exp2f(x)
#else
  #define EXP2(x) exp2f(x)
#endif

// packed f32x2 -> bf16x2 (RNE), low half = src0
__device__ __forceinline__ unsigned cvtpk_bf16(float lo, float hi) {
  unsigned r;
  asm("v_cvt_pk_bf16_f32 %0, %1, %2" : "=v"(r) : "v"(lo), "v"(hi));
  return r;
}

// async global->LDS 16B per lane (dest = wave-uniform base + lane*16)
__device__ __forceinline__ void gload_lds16(const void* g, void* l) {
  __builtin_amdgcn_global_load_lds(
      (const __attribute__((address_space(1))) unsigned*)g,
      (__attribute__((address_space(3))) unsigned*)l, 16, 0, 0);
}

// ---------------------------------------------------------------------------
// Kernel 0b: cast embed_w -> wbf [384][256] bf16 ; transpose out_w -> w2t [256][128] bf16
// ---------------------------------------------------------------------------
__global__ __launch_bounds__(256) void k_prep_w(const float* __restrict__ ew,
                                                const float* __restrict__ ow,
                                                u16* __restrict__ wbf,
                                                u16* __restrict__ w2t) {
  int i = blockIdx.x * 256 + threadIdx.x;
  if (i < 384 * 256) wbf[i] = f2bf(ew[i]);
  if (i < 128 * 256) {
    int d = i >> 8, c = i & 255;              // out_w[d][c]
    w2t[c * 128 + d] = f2bf(ow[i]);
  }
}

// ---------------------------------------------------------------------------
// Kernel 1: fused transpose + QKV projection (round-10 proven).
//   q -> Qt [bh][N][64] (n-major, pre-scaled by C^-0.5 * log2(e))
//   k -> Kt [bh][N][64] (n-major)
//   v -> Vs [bh][nt(64)][kk(2)][lg(4)][c(64)][8]  (PV-fragment order)
// ---------------------------------------------------------------------------
__global__ __launch_bounds__(256) void k_qkv(const float* __restrict__ x,
                                             const u16* __restrict__ wbf,
                                             const float* __restrict__ eb,
                                             u16* __restrict__ Qt,
                                             u16* __restrict__ Kt,
                                             u16* __restrict__ Vs) {
  int id = blockIdx.x;          // 512
  int xcd = id & 7;
  int b = xcd >> 1, h = xcd & 1;
  int nt = id >> 3;             // 0..63
  int tid = threadIdx.x;        // 0..255
  int w = tid >> 6, l = tid & 63, lr = l & 15, lg = l >> 4;

  __shared__ __align__(16) u16 Xl[64 * 256];   // 32 KB: Xl[n][c], slot-swizzled

  const float* xb = x + (size_t)b * C_IN * N_POS + nt*64;
  {
    int n = l;                   // lane = n
#pragma unroll
    for (int pass = 0; pass < 8; pass++) {
      int oct = w + pass*4;      // c-oct 0..31 (8 channels each)
      int cb8 = oct * 8;
      float v[8];
#pragma unroll
      for (int j = 0; j < 8; j++) v[j] = xb[(size_t)(cb8 + j) * N_POS + n];
      union { bf16x8 vv; unsigned u[4]; } pk;
#pragma unroll
      for (int jj = 0; jj < 4; jj++) pk.u[jj] = cvtpk_bf16(v[2*jj], v[2*jj+1]);
      int slot = oct ^ ((n & 7) << 2);
      *(bf16x8*)&Xl[n * 256 + slot * 8] = pk.vv;
    }
  }
  __syncthreads();

  f32x4 acc[4][3] = {};
  const u16* brow[3];
#pragma unroll
  for (int i = 0; i < 3; i++)
    brow[i] = wbf + (size_t)(h*192 + (3*w + i)*16 + lr) * C_IN + lg*8;

#pragma unroll
  for (int kk = 0; kk < 8; kk++) {
    bf16x8 bfr[3];
#pragma unroll
    for (int i = 0; i < 3; i++) bfr[i] = *(const bf16x8*)(brow[i] + kk*32);
#pragma unroll
    for (int nsub = 0; nsub < 4; nsub++) {
      int n2 = nsub*16 + lr;
      int sp = (kk*4 + lg) ^ ((lr & 7) << 2);
      bf16x8 a = *(const bf16x8*)&Xl[n2*256 + sp*8];
#pragma unroll
      for (int i = 0; i < 3; i++)
        acc[nsub][i] = __builtin_amdgcn_mfma_f32_16x16x32_bf16(a, bfr[i], acc[nsub][i], 0, 0, 0);
    }
  }

  const float QSCALE = 0.0625f * 1.44269504088896f;  // C^-0.5 * log2(e)
  int bh = b * NH + h;
#pragma unroll
  for (int i = 0; i < 3; i++) {
    int s3 = 3*w + i;
    int type = s3 >> 2, mf = s3 & 3;
    int cl = mf*16 + lr;                       // channel within head [0,64)
    float bias = eb[h*192 + type*64 + cl];
#pragma unroll
    for (int nsub = 0; nsub < 4; nsub++) {
      int n0 = nt*64 + nsub*16 + lg*4;         // 4 consecutive n (regs)
      if (type == 0) {
        u16* q = Qt + (size_t)bh * N_POS * HC;
#pragma unroll
        for (int r = 0; r < 4; r++) q[(size_t)(n0+r)*HC + cl] = f2bf((acc[nsub][i][r] + bias) * QSCALE);
      } else if (type == 1) {
        u16* kd = Kt + (size_t)bh * N_POS * HC;
#pragma unroll
        for (int r = 0; r < 4; r++) kd[(size_t)(n0+r)*HC + cl] = f2bf(acc[nsub][i][r] + bias);
      } else {
        u16* vd = Vs + (size_t)bh * (N_POS * HC);
        size_t idx = ((((size_t)nt*2 + (nsub>>1))*4 + lg)*64 + cl)*8 + 4*(nsub&1);
        ushort4 pk;
        pk.x = f2bf(acc[nsub][i][0] + bias);
        pk.y = f2bf(acc[nsub][i][1] + bias);
        pk.z = f2bf(acc[nsub][i][2] + bias);
        pk.w = f2bf(acc[nsub][i][3] + bias);
        *(ushort4*)(vd + idx) = pk;
      }
    }
  }
}

// ---------------------------------------------------------------------------
// Kernel 2: flash attention (round-10 proven structure). 16 waves = 4 qi x 4 ci,
// QBLK=32 rows/wave, double-buffered global_load_lds staging, grid 256.
// + rotated merge layout (bank-conflict-free) + setprio on MFMA clusters.
// ---------------------------------------------------------------------------
__device__ __forceinline__ void softmax_tile(f32x4 (&s)[4], f32x4& psv, float& rm,
                                             f32x4 (&o)[4]) {
  float mx = s[0][0];
#pragma unroll
  for (int nf = 0; nf < 4; nf++)
#pragma unroll
    for (int r = 0; r < 4; r++) mx = fmaxf(mx, s[nf][r]);
  mx = fmaxf(mx, __shfl_xor(mx, 16));
  mx = fmaxf(mx, __shfl_xor(mx, 32));
  float nm = fmaxf(rm, mx);
  float corr = EXP2(rm - nm);
  rm = nm;
#pragma unroll
  for (int r = 0; r < 4; r++) psv[r] *= corr;
#pragma unroll
  for (int nf = 0; nf < 4; nf++)
#pragma unroll
    for (int r = 0; r < 4; r++) {
      float p = EXP2(s[nf][r] - nm);
      s[nf][r] = p;
      psv[r] += p;
    }
#pragma unroll
  for (int cf = 0; cf < 4; cf++)
#pragma unroll
    for (int r = 0; r < 4; r++) o[cf][r] *= corr;
}

__global__ __launch_bounds__(1024, 4) void k_attn(const u16* __restrict__ Qt,
                                                  const u16* __restrict__ Kt,
                                                  const u16* __restrict__ Vs,
                                                  u16* __restrict__ Ot) {
  int id = blockIdx.x;            // 256
  int bh = id & 7;                // XCD-swizzle: one (b,h) per XCD
  int mt = id >> 3;               // 32 q-tiles of 128 rows
  int b = bh >> 1, h = bh & 1;
  int tid = threadIdx.x;
  int wid = tid >> 6;             // 0..15
  int l = tid & 63, lr = l & 15, lg = l >> 4;
  int qi = wid & 3;               // 32-row q-subtile
  int ci = wid >> 2;              // KV chunk (16 tiles of 64 = 1024 positions)
  int m0 = mt*128 + qi*32;

  // 128KB staging: [buf2][ci4][ K 8KB | V 8KB ]; merge overlays after loop
  __shared__ __align__(16) char smem[131072];
  __shared__ float Lps[4][8][16];
  __shared__ float Lm[4][8][16];

  bf16x8 qf[2][2];
#pragma unroll
  for (int sub = 0; sub < 2; sub++) {
    const u16* qb = Qt + ((size_t)bh * N_POS + m0 + sub*16 + lr) * HC + lg*8;
    qf[sub][0] = *(const bf16x8*)qb;
    qf[sub][1] = *(const bf16x8*)(qb + 32);
  }

  const char* Kt_bh = (const char*)(Kt + (size_t)bh * N_POS * HC);
  const char* Vs_bh = (const char*)(Vs + (size_t)bh * N_POS * HC);
  int gtid = tid & 255;           // index within ci staging group (256 threads)

  f32x4 o0[4] = {}, o1[4] = {};
  f32x4 ps0 = {}, ps1 = {};
  float rm0 = -1e30f, rm1 = -1e30f;
  int xr = (lr & 7) << 4;         // K read swizzle

  union PF { bf16x8 v; unsigned u[4]; };

  // stage tile -> LDS: K with inverse-swizzled SOURCE (linear dest), V linear
  auto stage = [&](int tile, char* sb) {
    const char* ksrc = Kt_bh + (size_t)tile * 8192;
    const char* vsrc = Vs_bh + (size_t)tile * 8192;
#pragma unroll
    for (int j = 0; j < 2; j++) {
      int off = (j*256 + gtid) * 16;
      int koff = off ^ (((off >> 7) & 7) << 4);
      gload_lds16(ksrc + koff, sb + off);
      gload_lds16(vsrc + off, sb + 8192 + off);
    }
  };

  stage(ci*16, smem + ci*16384);
  __syncthreads();

  int buf = 0;
  for (int t = 0; t < 16; t++) {
    if (t < 15) stage(ci*16 + t + 1, smem + (buf^1)*65536 + ci*16384);

    const char* Kb = smem + buf*65536 + ci*16384;
    const char* Vb = Kb + 8192;

    // ---- S^T = K . Q^T for both q-subtiles (K read once) ----
    f32x4 s0[4], s1[4];
    __builtin_amdgcn_s_setprio(1);
#pragma unroll
    for (int nf = 0; nf < 4; nf++) {
      const char* kr = Kb + (nf*16 + lr) * 128;
      bf16x8 k0 = *(const bf16x8*)(kr + ((lg*16)      ^ xr));
      bf16x8 k1 = *(const bf16x8*)(kr + ((lg*16 + 64) ^ xr));
      f32x4 z0 = {}, z1 = {};
      z0 = __builtin_amdgcn_mfma_f32_16x16x32_bf16(k0, qf[0][0], z0, 0, 0, 0);
      s0[nf] = __builtin_amdgcn_mfma_f32_16x16x32_bf16(k1, qf[0][1], z0, 0, 0, 0);
      z1 = __builtin_amdgcn_mfma_f32_16x16x32_bf16(k0, qf[1][0], z1, 0, 0, 0);
      s1[nf] = __builtin_amdgcn_mfma_f32_16x16x32_bf16(k1, qf[1][1], z1, 0, 0, 0);
    }
    __builtin_amdgcn_s_setprio(0);

    softmax_tile(s0, ps0, rm0, o0);
    softmax_tile(s1, ps1, rm1, o1);

    // ---- O^T += V^T . P (V read once, feeds both subtiles) ----
    __builtin_amdgcn_s_setprio(1);
#pragma unroll
    for (int kk = 0; kk < 2; kk++) {
      PF pa, pb;
      pa.u[0] = cvtpk_bf16(s0[2*kk+0][0], s0[2*kk+0][1]);
      pa.u[1] = cvtpk_bf16(s0[2*kk+0][2], s0[2*kk+0][3]);
      pa.u[2] = cvtpk_bf16(s0[2*kk+1][0], s0[2*kk+1][1]);
      pa.u[3] = cvtpk_bf16(s0[2*kk+1][2], s0[2*kk+1][3]);
      pb.u[0] = cvtpk_bf16(s1[2*kk+0][0], s1[2*kk+0][1]);
      pb.u[1] = cvtpk_bf16(s1[2*kk+0][2], s1[2*kk+0][3]);
      pb.u[2] = cvtpk_bf16(s1[2*kk+1][0], s1[2*kk+1][1]);
      pb.u[3] = cvtpk_bf16(s1[2*kk+1][2], s1[2*kk+1][3]);
#pragma unroll
      for (int cf = 0; cf < 4; cf++) {
        bf16x8 vf = *(const bf16x8*)(Vb + (kk*4 + lg)*1024 + (cf*16 + lr)*16);
        o0[cf] = __builtin_amdgcn_mfma_f32_16x16x32_bf16(vf, pa.v, o0[cf], 0, 0, 0);
        o1[cf] = __builtin_amdgcn_mfma_f32_16x16x32_bf16(vf, pb.v, o1[cf], 0, 0, 0);
      }
    }
    __builtin_amdgcn_s_setprio(0);

    __syncthreads();   // drains vmcnt -> next buffer ready
    buf ^= 1;
  }

  // ---- chunk-partial row sums ----
  float psa = ps0[0] + ps0[1] + ps0[2] + ps0[3];
  psa += __shfl_xor(psa, 16);
  psa += __shfl_xor(psa, 32);
  float psb = ps1[0] + ps1[1] + ps1[2] + ps1[3];
  psb += __shfl_xor(psb, 16);
  psb += __shfl_xor(psb, 32);

  // ---- write partials (Lo overlays staging LDS; row-rotated cols) ----
  float (*Lo)[8][16][64] = (float (*)[8][16][64])smem;
#pragma unroll
  for (int cf = 0; cf < 4; cf++) {
    int colw = ((cf*16 + 4*lg) + 4*lr) & 63;
    *(f32x4*)&Lo[ci][qi*2+0][lr][colw] = o0[cf];
    *(f32x4*)&Lo[ci][qi*2+1][lr][colw] = o1[cf];
  }
  if (lg == 0) {
    Lps[ci][qi*2+0][lr] = psa; Lm[ci][qi*2+0][lr] = rm0;
    Lps[ci][qi*2+1][lr] = psb; Lm[ci][qi*2+1][lr] = rm1;
  }
  __syncthreads();

  // ---- exact flash merge of 4 chunks + normalize + write Ot [B][N][128] ----
  int row = tid >> 3;             // 0..127 within this q-tile
  int c0 = (tid & 7) * 8;         // 0..56
  int g = row >> 4, r2 = row & 15;
  float m0_ = Lm[0][g][r2], m1_ = Lm[1][g][r2];
  float m2_ = Lm[2][g][r2], m3_ = Lm[3][g][r2];
  float M = fmaxf(fmaxf(m0_, m1_), fmaxf(m2_, m3_));
  float w0 = EXP2(m0_ - M), w1 = EXP2(m1_ - M);
  float w2 = EXP2(m2_ - M), w3 = EXP2(m3_ - M);
  int ca = (c0 + 4*r2) & 63;      // rotated col of channels c0..c0+3
  int cb = (c0 + 4 + 4*r2) & 63;  // rotated col of channels c0+4..c0+7
  f32x4 accA, accB;
  {
    f32x4 a0 = *(const f32x4*)&Lo[0][g][r2][ca];
    f32x4 a1 = *(const f32x4*)&Lo[1][g][r2][ca];
    f32x4 a2 = *(const f32x4*)&Lo[2][g][r2][ca];
    f32x4 a3 = *(const f32x4*)&Lo[3][g][r2][ca];
#pragma unroll
    for (int i = 0; i < 4; i++) accA[i] = a0[i]*w0 + a1[i]*w1 + a2[i]*w2 + a3[i]*w3;
    f32x4 b0 = *(const f32x4*)&Lo[0][g][r2][cb];
    f32x4 b1 = *(const f32x4*)&Lo[1][g][r2][cb];
    f32x4 b2 = *(const f32x4*)&Lo[2][g][r2][cb];
    f32x4 b3 = *(const f32x4*)&Lo[3][g][r2][cb];
#pragma unroll
    for (int i = 0; i < 4; i++) accB[i] = b0[i]*w0 + b1[i]*w1 + b2[i]*w2 + b3[i]*w3;
  }
  float pst = Lps[0][g][r2]*w0 + Lps[1][g][r2]*w1
            + Lps[2][g][r2]*w2 + Lps[3][g][r2]*w3;
  float rinv = 1.0f / pst;
  u16* ob = Ot + ((size_t)b * N_POS + mt*128 + row) * (NH*HC) + h*HC + c0;
  uint4 st;
  st.x = cvtpk_bf16(accA[0]*rinv, accA[1]*rinv);
  st.y = cvtpk_bf16(accA[2]*rinv, accA[3]*rinv);
  st.z = cvtpk_bf16(accB[0]*rinv, accB[1]*rinv);
  st.w = cvtpk_bf16(accB[2]*rinv, accB[3]*rinv);
  *(uint4*)ob = st;
}

// ---------------------------------------------------------------------------
// Kernel 3: out[b][c][n] = sum_d Ot[n][d] * w2t[c][d] + out_b[c] + x[b][c][n]
// ---------------------------------------------------------------------------
__global__ __launch_bounds__(256) void k_out(const u16* __restrict__ Ot,
                                             const u16* __restrict__ w2t,
                                             const float* __restrict__ obias,
                                             const float* __restrict__ x,
                                             float* __restrict__ out) {
  int b = blockIdx.z;   // 4
  int ct = blockIdx.y;  // 4
  int nt = blockIdx.x;  // 64
  int w = threadIdx.x >> 6, l = threadIdx.x & 63;
  int lr = l & 15, lg = l >> 4;

  const u16* arow = Ot + ((size_t)b * N_POS + nt*64 + w*16 + lr) * 128 + lg*8;
  const u16* brow = w2t + ((size_t)(ct*64) + lr) * 128 + lg*8;

  f32x4 acc[4] = {};
#pragma unroll
  for (int kk = 0; kk < 4; kk++) {
    bf16x8 a = *(const bf16x8*)(arow + kk*32);
#pragma unroll
    for (int cf = 0; cf < 4; cf++) {
      bf16x8 bf = *(const bf16x8*)(brow + (size_t)cf*16*128 + kk*32);
      acc[cf] = __builtin_amdgcn_mfma_f32_16x16x32_bf16(a, bf, acc[cf], 0, 0, 0);
    }
  }

  int n0 = nt*64 + w*16 + lg*4;
#pragma unroll
  for (int cf = 0; cf < 4; cf++) {
    int c = ct*64 + cf*16 + lr;
    float bias = obias[c];
    const float* xp = x + ((size_t)b * C_IN + c) * N_POS + n0;
    float* op = out + ((size_t)b * C_IN + c) * N_POS + n0;
    f32x4 xv = *(const f32x4*)xp;
    f32x4 rv;
#pragma unroll
    for (int i = 0; i < 4; i++) rv[i] = acc[cf][i] + bias + xv[i];
    *(f32x4*)op = rv;
  }
}

// ---------------------------------------------------------------------------
extern "C" void kernel_launch(void* const* d_in, const int* in_sizes, int n_in,
                              void* d_out, int out_size, void* d_ws, size_t ws_size,
                              hipStream_t stream) {
  const float* x  = (const float*)d_in[0];   // [4,256,64,64]
  const float* ew = (const float*)d_in[1];   // [2,192,256]
  const float* eb = (const float*)d_in[2];   // [2,192]
  const float* ow = (const float*)d_in[3];   // [128,256]
  const float* ob = (const float*)d_in[4];   // [256]
  float* out = (float*)d_out;

  char* ws = (char*)d_ws;
  u16* wbf = (u16*)(ws + 0);          //    196,608 B  embed_w bf16 [384][256]
  u16* w2t = (u16*)(ws + 196608);     //     65,536 B  out_w^T bf16 [256][128]
  u16* Qt  = (u16*)(ws + 262144);     //  4,194,304 B  [8][4096][64]
  u16* Kt  = (u16*)(ws + 4456448);    //  4,194,304 B  [8][4096][64]
  u16* Vs  = (u16*)(ws + 8650752);    //  4,194,304 B  permuted V
  u16* Ot  = (u16*)(ws + 12845056);   //  4,194,304 B  [B][N][128]

  hipLaunchKernelGGL(k_prep_w, dim3(384), dim3(256), 0, stream, ew, ow, wbf, w2t);
  hipLaunchKernelGGL(k_qkv,  dim3(512),      dim3(256), 0, stream, x, wbf, eb, Qt, Kt, Vs);
  hipLaunchKernelGGL(k_attn, dim3(256),      dim3(1024), 0, stream, Qt, Kt, Vs, Ot);
  hipLaunchKernelGGL(k_out,  dim3(64, 4, 4), dim3(256), 0, stream, Ot, w2t, ob, x, out);
}